// Round 6
// baseline (1773.309 us; speedup 1.0000x reference)
//
#include <hip/hip_runtime.h>

#define D_MODEL 1024
#define NHEADS  16
#define DK      64
#define S_LEN   2048
#define BATCH   4
#define BH      (BATCH * NHEADS)     // 64
#define M_ROWS  (BATCH * S_LEN)      // 8192

typedef float  f32x4 __attribute__((ext_vector_type(4)));
typedef short  s16x8 __attribute__((ext_vector_type(8)));
typedef unsigned short u16;
typedef u16 us8 __attribute__((ext_vector_type(8)));

__device__ __forceinline__ u16 f2bf(float f) {
    unsigned u = __builtin_bit_cast(unsigned, f);
    u += 0x7FFFu + ((u >> 16) & 1u);
    return (u16)(u >> 16);
}
__device__ __forceinline__ float bf2f(u16 b) {
    unsigned u = ((unsigned)b) << 16;
    return __builtin_bit_cast(float, u);
}

// compat = (1 + sqrt(max(d2,0))/64)^(-65) = exp2(-65 * log2(p))
__device__ __forceinline__ float compat_fn(float d2) {
    float g = __builtin_amdgcn_sqrtf(fmaxf(d2, 0.0f)) * 0.015625f;
    float p = 1.0f + g;
    return __builtin_amdgcn_exp2f(-65.0f * __builtin_amdgcn_logf(p));
}

__device__ __forceinline__ void gll16(const void* g, void* l) {
    __builtin_amdgcn_global_load_lds(
        (const __attribute__((address_space(1))) void*)g,
        (__attribute__((address_space(3))) void*)l, 16, 0, 0);
}

#define MFMA_BF16(a, b, c) __builtin_amdgcn_mfma_f32_16x16x32_bf16(a, b, c, 0, 0, 0)

// fp32 -> (hi, lo) bf16 split, 8 elements per thread
__global__ __launch_bounds__(256) void split_bf16(const float* __restrict__ in,
                                                  u16* __restrict__ hi,
                                                  u16* __restrict__ lo, int n8) {
    int i = blockIdx.x * 256 + threadIdx.x;
    if (i >= n8) return;
    const float4* p = (const float4*)in;
    float4 a = p[i * 2], b = p[i * 2 + 1];
    float v[8] = {a.x, a.y, a.z, a.w, b.x, b.y, b.z, b.w};
    us8 h, l;
#pragma unroll
    for (int j = 0; j < 8; ++j) {
        u16 hb = f2bf(v[j]);
        h[j] = hb;
        l[j] = f2bf(v[j] - bf2f(hb));
    }
    ((us8*)hi)[i] = h;
    ((us8*)lo)[i] = l;
}

// Split-bf16 MFMA GEMM: out = A @ B^T (+bias).
// MODE 0: head-split hi/lo bf16  dst[((b*16+h)*2048+s)*64+d]
// MODE 2: head-split TRANSPOSED bf16 (HI ONLY) dst[((b*16+h)*64+d)*2048+t]
// MODE 1: fp32 outf[m*1024+n] = acc + bias[n]
template <int MODE>
__global__ __launch_bounds__(256, 2) void proj_mfma(
    const u16* __restrict__ Ah, const u16* __restrict__ Al,
    const u16* __restrict__ Bh, const u16* __restrict__ Bl,
    const float* __restrict__ bias,
    float* __restrict__ outf, u16* __restrict__ ohi, u16* __restrict__ olo) {
    __shared__ __align__(16) u16 lds[4 * 128 * 64];   // 64 KB
    u16* LAh = lds;
    u16* LAl = lds + 8192;
    u16* LBh = lds + 16384;
    u16* LBl = lds + 24576;

    const int tid  = threadIdx.x;
    const int wave = tid >> 6, lane = tid & 63;
    const int wm = wave >> 1, wn = wave & 1;
    const int l15 = lane & 15, lg = lane >> 4;
    // XCD swizzle: 512 blocks, 64 per XCD chunk
    const int flat = blockIdx.y * 8 + blockIdx.x;
    const int swz  = (flat & 7) * 64 + (flat >> 3);
    const int n0 = (swz & 7) * 128;
    const int m0 = (swz >> 3) * 128;

    const int srow = wave * 32 + (lane >> 3);
    const int scol = (lane & 7) * 8;

    f32x4 acc[4][4];
#pragma unroll
    for (int i = 0; i < 4; ++i)
#pragma unroll
        for (int j = 0; j < 4; ++j) acc[i][j] = (f32x4){0.f, 0.f, 0.f, 0.f};

#pragma unroll 1
    for (int k0 = 0; k0 < D_MODEL; k0 += 64) {
        __syncthreads();
#pragma unroll
        for (int q = 0; q < 4; ++q) {
            const size_t ga = (size_t)(m0 + srow + q * 8) * D_MODEL + k0 + scol;
            const size_t gb = (size_t)(n0 + srow + q * 8) * D_MODEL + k0 + scol;
            gll16(Ah + ga, LAh + wave * 2048 + q * 512);
            gll16(Al + ga, LAl + wave * 2048 + q * 512);
            gll16(Bh + gb, LBh + wave * 2048 + q * 512);
            gll16(Bl + gb, LBl + wave * 2048 + q * 512);
        }
        __syncthreads();
#pragma unroll
        for (int kc = 0; kc < 2; ++kc) {
            s16x8 ah[4], al[4];
#pragma unroll
            for (int fm = 0; fm < 4; ++fm) {
                const int r = wm * 64 + fm * 16 + l15;
                ah[fm] = *(const s16x8*)&LAh[r * 64 + kc * 32 + lg * 8];
                al[fm] = *(const s16x8*)&LAl[r * 64 + kc * 32 + lg * 8];
            }
#pragma unroll
            for (int fn = 0; fn < 4; ++fn) {
                const int r = wn * 64 + fn * 16 + l15;
                s16x8 bh = *(const s16x8*)&LBh[r * 64 + kc * 32 + lg * 8];
                s16x8 bl = *(const s16x8*)&LBl[r * 64 + kc * 32 + lg * 8];
#pragma unroll
                for (int fm = 0; fm < 4; ++fm) {
                    acc[fm][fn] = MFMA_BF16(ah[fm], bh, acc[fm][fn]);
                    acc[fm][fn] = MFMA_BF16(ah[fm], bl, acc[fm][fn]);
                    acc[fm][fn] = MFMA_BF16(al[fm], bh, acc[fm][fn]);
                }
            }
        }
    }
    __syncthreads();   // LDS free for epilogue reuse

    if (MODE == 0) {
        const int h = (n0 >> 6) + wn;
#pragma unroll
        for (int fm = 0; fm < 4; ++fm)
#pragma unroll
            for (int i = 0; i < 4; ++i) {
                const int m = m0 + wm * 64 + fm * 16 + lg * 4 + i;
                const int b = m >> 11, s = m & 2047;
                const size_t rb = ((size_t)((b * NHEADS + h) * S_LEN + s)) * DK;
#pragma unroll
                for (int fn = 0; fn < 4; ++fn) {
                    float v = acc[fm][fn][i];
                    u16 hb = f2bf(v);
                    u16 lb = f2bf(v - bf2f(hb));
                    ohi[rb + fn * 16 + l15] = hb;
                    olo[rb + fn * 16 + l15] = lb;
                }
            }
    } else if (MODE == 1) {
#pragma unroll
        for (int fm = 0; fm < 4; ++fm)
#pragma unroll
            for (int i = 0; i < 4; ++i) {
                const int m = m0 + wm * 64 + fm * 16 + lg * 4 + i;
#pragma unroll
                for (int fn = 0; fn < 4; ++fn) {
                    const int n = n0 + wn * 64 + fn * 16 + l15;
                    outf[(size_t)m * D_MODEL + n] = acc[fm][fn][i] + bias[n];
                }
            }
    } else {   // MODE 2: per-wave 64x64 transpose, HI only -> VT[bh][d][t]
        const int h  = (n0 >> 6) + wn;
        const int b  = m0 >> 11;
        const int bh = b * NHEADS + h;
        const int t_base = (m0 & 2047) + wm * 64;
        u16* T = lds + wave * 4096;   // [64][64] = [d_local][t_local]
#pragma unroll
        for (int fm = 0; fm < 4; ++fm)
#pragma unroll
            for (int fn = 0; fn < 4; ++fn)
#pragma unroll
                for (int i = 0; i < 4; ++i)
                    T[(fn * 16 + l15) * 64 + fm * 16 + lg * 4 + i] = f2bf(acc[fm][fn][i]);
        __syncthreads();
#pragma unroll
        for (int j = 0; j < 8; ++j) {
            const int cid = j * 64 + lane;
            const int dr = cid >> 3;
            const int cc = (cid & 7) * 8;
            us8 v8 = *(const us8*)&T[dr * 64 + cc];
            *(us8*)&ohi[((size_t)(bh * DK + dr)) * S_LEN + t_base + cc] = v8;
        }
    }
}

// squared L2 norms of Q rows and K rows from hi+lo bf16; one wave per row
__global__ __launch_bounds__(256) void row_norms(const u16* __restrict__ Qhi,
                                                 const u16* __restrict__ Qlo,
                                                 const u16* __restrict__ Khi,
                                                 const u16* __restrict__ Klo,
                                                 float* __restrict__ q2,
                                                 float* __restrict__ k2) {
    int wid  = blockIdx.x * 4 + (threadIdx.x >> 6);
    int lane = threadIdx.x & 63;
    const u16 *hi, *lo; float* dstp; int row;
    if (wid < BH * S_LEN) { hi = Qhi; lo = Qlo; dstp = q2; row = wid; }
    else                  { hi = Khi; lo = Klo; dstp = k2; row = wid - BH * S_LEN; }
    float v = bf2f(hi[(size_t)row * DK + lane]) + bf2f(lo[(size_t)row * DK + lane]);
    float s = v * v;
#pragma unroll
    for (int off = 32; off > 0; off >>= 1) s += __shfl_xor(s, off);
    if (lane == 0) dstp[row] = s;
}

// Pass A: column sums -> CV[t] = NC[t]^-0.5. Single-bf16 QK. Q-tile prefetched
// one iter ahead; compat DEFERRED one iter (overlaps MFMA drain); XCD swizzle.
__global__ __launch_bounds__(256, 4) void colsum_mfma(
    const u16* __restrict__ Qhi, const u16* __restrict__ Khi,
    const float* __restrict__ q2, const float* __restrict__ k2,
    float* __restrict__ CV) {
    const int tid  = threadIdx.x;
    const int wave = tid >> 6, lane = tid & 63;
    const int ws = wave >> 1, wt = wave & 1;
    const int l15 = lane & 15, lg = lane >> 4;
    const int flat = blockIdx.y * 32 + blockIdx.x;
    const int swz  = (flat & 7) * 256 + (flat >> 3);
    const int bh = swz >> 5;
    const int t0 = (swz & 31) * 64;
    const size_t base = (size_t)bh * S_LEN * DK;
    const u16* Kh = Khi + base;
    const u16* Qh = Qhi + base;
    const float* q2b = q2 + (size_t)bh * S_LEN;
    const float* k2b = k2 + (size_t)bh * S_LEN;

    s16x8 kh[2][2];
    float k2v[2];
#pragma unroll
    for (int ft = 0; ft < 2; ++ft) {
        const int tr = t0 + wt * 32 + ft * 16 + l15;
#pragma unroll
        for (int kc = 0; kc < 2; ++kc)
            kh[ft][kc] = *(const s16x8*)(Kh + (size_t)tr * DK + kc * 32 + lg * 8);
        k2v[ft] = k2b[tr];
    }

    s16x8 qh[2][2];
    auto loadQ = [&](int sb) {
#pragma unroll
        for (int fs = 0; fs < 2; ++fs) {
            const int qr = sb + fs * 16 + l15;
#pragma unroll
            for (int kc = 0; kc < 2; ++kc)
                qh[fs][kc] = *(const s16x8*)(Qh + (size_t)qr * DK + kc * 32 + lg * 8);
        }
    };
    loadQ(ws * 32);

    float colacc[2] = {0.f, 0.f};
    f32x4 accP[2][2];        // pipeline state: previous iter's QK acc
    float4 q2P[2];

#pragma unroll 1
    for (int s0 = 0; s0 < S_LEN; s0 += 64) {
        const int sb = s0 + ws * 32;
        float4 q2c[2];
#pragma unroll
        for (int fs = 0; fs < 2; ++fs)
            q2c[fs] = *(const float4*)&q2b[sb + fs * 16 + lg * 4];

        f32x4 accC[2][2];
#pragma unroll
        for (int fs = 0; fs < 2; ++fs)
#pragma unroll
            for (int ft = 0; ft < 2; ++ft) {
                accC[fs][ft] = (f32x4){0.f, 0.f, 0.f, 0.f};
#pragma unroll
                for (int kc = 0; kc < 2; ++kc)
                    accC[fs][ft] = MFMA_BF16(qh[fs][kc], kh[ft][kc], accC[fs][ft]);
            }
        if (s0 + 64 < S_LEN) loadQ(s0 + 64 + ws * 32);   // prefetch next s-tile

        if (s0 > 0) {   // deferred compat on PREVIOUS acc (MFMAs above drain)
#pragma unroll
            for (int fs = 0; fs < 2; ++fs)
#pragma unroll
                for (int ft = 0; ft < 2; ++ft)
#pragma unroll
                    for (int i = 0; i < 4; ++i) {
                        float d2 = q2P[fs][i] + k2v[ft] - 2.0f * accP[fs][ft][i];
                        colacc[ft] += compat_fn(d2);
                    }
        }
#pragma unroll
        for (int fs = 0; fs < 2; ++fs) {
            q2P[fs] = q2c[fs];
#pragma unroll
            for (int ft = 0; ft < 2; ++ft) accP[fs][ft] = accC[fs][ft];
        }
    }
    // epilogue: compat for the last s-tile
#pragma unroll
    for (int fs = 0; fs < 2; ++fs)
#pragma unroll
        for (int ft = 0; ft < 2; ++ft)
#pragma unroll
            for (int i = 0; i < 4; ++i) {
                float d2 = q2P[fs][i] + k2v[ft] - 2.0f * accP[fs][ft][i];
                colacc[ft] += compat_fn(d2);
            }

#pragma unroll
    for (int ft = 0; ft < 2; ++ft) {
        colacc[ft] += __shfl_xor(colacc[ft], 16);
        colacc[ft] += __shfl_xor(colacc[ft], 32);
    }
    __shared__ float cs[4][64];
    if (lg == 0) {
        cs[wave][wt * 32 + l15]      = colacc[0];
        cs[wave][wt * 32 + 16 + l15] = colacc[1];
    }
    __syncthreads();
    if (tid < 64) {
        int wtj = tid >> 5;
        float s = cs[wtj][tid] + cs[wtj + 2][tid];
        CV[(size_t)bh * S_LEN + t0 + tid] = 1.0f / __builtin_amdgcn_sqrtf(s);
    }
}

// Pass B: flash-style (r4 structure) + one-iter compat/PV DEFERRAL:
// QK(i) issues, then compat(i-1) VALU runs while MFMAs drain, barrier,
// PV(i-1) with V(i-1) kept in registers. Every load has a full iter of slack.
__global__ __launch_bounds__(256, 4) void attn_mfma(
    const u16* __restrict__ Qhi, const u16* __restrict__ Qlo,
    const u16* __restrict__ Khi, const u16* __restrict__ Klo,
    const u16* __restrict__ VThi,
    const float* __restrict__ q2, const float* __restrict__ k2,
    const float* __restrict__ CV,
    u16* __restrict__ ATTNhi, u16* __restrict__ ATTNlo) {
    __shared__ __align__(16) u16 Wb[2][64][72];   // double-buffered [s][t]
    __shared__ float rsum[2][64];
    const int tid  = threadIdx.x;
    const int wave = tid >> 6, lane = tid & 63;
    const int ws = wave >> 1, wt = wave & 1;
    const int l15 = lane & 15, lg = lane >> 4;
    const int flat = blockIdx.y * 32 + blockIdx.x;
    const int swz  = (flat & 7) * 256 + (flat >> 3);
    const int bh = swz >> 5;
    const int s0 = (swz & 31) * 64;
    const int b = bh >> 4, h = bh & 15;
    const size_t base = (size_t)bh * S_LEN * DK;
    const u16* Qh = Qhi + base;
    const u16* Ql = Qlo + base;
    const u16* Kh = Khi + base;
    const u16* Kl = Klo + base;
    const u16* Vh = VThi + base;   // per-bh [64][2048]
    const float* q2b = q2 + (size_t)bh * S_LEN;
    const float* k2b = k2 + (size_t)bh * S_LEN;
    const float* CVb = CV + (size_t)bh * S_LEN;

    s16x8 qh[2][2], qlr[2][2];
#pragma unroll
    for (int fs = 0; fs < 2; ++fs) {
        const int qr = s0 + ws * 32 + fs * 16 + l15;
#pragma unroll
        for (int kc = 0; kc < 2; ++kc) {
            qh[fs][kc]  = *(const s16x8*)(Qh + (size_t)qr * DK + kc * 32 + lg * 8);
            qlr[fs][kc] = *(const s16x8*)(Ql + (size_t)qr * DK + kc * 32 + lg * 8);
        }
    }
    float q2v[2][4];
#pragma unroll
    for (int fs = 0; fs < 2; ++fs)
#pragma unroll
        for (int i = 0; i < 4; ++i)
            q2v[fs][i] = q2b[s0 + ws * 32 + fs * 16 + lg * 4 + i];

    s16x8 kh[2][2], kl[2][2];
    auto loadK = [&](int tc) {
#pragma unroll
        for (int ft = 0; ft < 2; ++ft) {
            const int tr = tc + wt * 32 + ft * 16 + l15;
#pragma unroll
            for (int kc = 0; kc < 2; ++kc) {
                kh[ft][kc] = *(const s16x8*)(Kh + (size_t)tr * DK + kc * 32 + lg * 8);
                kl[ft][kc] = *(const s16x8*)(Kl + (size_t)tr * DK + kc * 32 + lg * 8);
            }
        }
    };
    loadK(0);

    f32x4 o[2][2];
#pragma unroll
    for (int fs = 0; fs < 2; ++fs)
#pragma unroll
        for (int fd = 0; fd < 2; ++fd)
            o[fs][fd] = (f32x4){0.f, 0.f, 0.f, 0.f};
    float rowacc[2][4] = {};

    // pipeline state (previous iter)
    f32x4 accP[2][2];
    s16x8 vP[2][2];
    float k2P[2], cvP[2];

#pragma unroll 1
    for (int it = 0; it < S_LEN / 64; ++it) {
        const int t0 = it * 64;
        // V (single-bf16) + scalars for CURRENT iter (consumed NEXT iter)
        s16x8 vv[2][2];
#pragma unroll
        for (int fd = 0; fd < 2; ++fd) {
            const int dr = wt * 32 + fd * 16 + l15;
#pragma unroll
            for (int kc = 0; kc < 2; ++kc)
                vv[fd][kc] = *(const s16x8*)(Vh + (size_t)dr * S_LEN + t0 + kc * 32 + lg * 8);
        }
        float k2c[2], cvc[2];
#pragma unroll
        for (int ft = 0; ft < 2; ++ft) {
            const int tr = t0 + wt * 32 + ft * 16 + l15;
            k2c[ft] = k2b[tr];
            cvc[ft] = CVb[tr];
        }

        // QK^T(cur) with K loaded LAST iter
        f32x4 accC[2][2];
#pragma unroll
        for (int fs = 0; fs < 2; ++fs)
#pragma unroll
            for (int ft = 0; ft < 2; ++ft) {
                accC[fs][ft] = (f32x4){0.f, 0.f, 0.f, 0.f};
#pragma unroll
                for (int kc = 0; kc < 2; ++kc) {
                    accC[fs][ft] = MFMA_BF16(qh[fs][kc],  kh[ft][kc], accC[fs][ft]);
                    accC[fs][ft] = MFMA_BF16(qh[fs][kc],  kl[ft][kc], accC[fs][ft]);
                    accC[fs][ft] = MFMA_BF16(qlr[fs][kc], kh[ft][kc], accC[fs][ft]);
                }
            }
        // prefetch NEXT K tile
        if (t0 + 64 < S_LEN) loadK(t0 + 64);

        if (it > 0) {
            // deferred compat on PREVIOUS acc (runs while QK(cur) drains)
            const int bufp = (it - 1) & 1;
#pragma unroll
            for (int fs = 0; fs < 2; ++fs)
#pragma unroll
                for (int ft = 0; ft < 2; ++ft)
#pragma unroll
                    for (int i = 0; i < 4; ++i) {
                        float d2 = q2v[fs][i] + k2P[ft] - 2.0f * accP[fs][ft][i];
                        float w  = compat_fn(d2) * cvP[ft];
                        rowacc[fs][i] += w;
                        Wb[bufp][ws * 32 + fs * 16 + lg * 4 + i][wt * 32 + ft * 16 + l15] = f2bf(w);
                    }
            __syncthreads();   // W[bufp] complete across waves

            // PV(prev): W fragments x V(prev)
            s16x8 wh[2][2];
#pragma unroll
            for (int fs = 0; fs < 2; ++fs) {
                const int sl = ws * 32 + fs * 16 + l15;
#pragma unroll
                for (int kc = 0; kc < 2; ++kc)
                    wh[fs][kc] = *(const s16x8*)&Wb[bufp][sl][kc * 32 + lg * 8];
            }
#pragma unroll
            for (int fs = 0; fs < 2; ++fs)
#pragma unroll
                for (int fd = 0; fd < 2; ++fd)
#pragma unroll
                    for (int kc = 0; kc < 2; ++kc)
                        o[fs][fd] = MFMA_BF16(wh[fs][kc], vP[fd][kc], o[fs][fd]);
        }

        // rotate pipeline state
#pragma unroll
        for (int fs = 0; fs < 2; ++fs)
#pragma unroll
            for (int ft = 0; ft < 2; ++ft) accP[fs][ft] = accC[fs][ft];
#pragma unroll
        for (int fd = 0; fd < 2; ++fd)
#pragma unroll
            for (int kc = 0; kc < 2; ++kc) vP[fd][kc] = vv[fd][kc];
#pragma unroll
        for (int ft = 0; ft < 2; ++ft) { k2P[ft] = k2c[ft]; cvP[ft] = cvc[ft]; }
    }

    // epilogue: compat + PV for the last iter
    {
        const int bufp = (S_LEN / 64 - 1) & 1;
#pragma unroll
        for (int fs = 0; fs < 2; ++fs)
#pragma unroll
            for (int ft = 0; ft < 2; ++ft)
#pragma unroll
                for (int i = 0; i < 4; ++i) {
                    float d2 = q2v[fs][i] + k2P[ft] - 2.0f * accP[fs][ft][i];
                    float w  = compat_fn(d2) * cvP[ft];
                    rowacc[fs][i] += w;
                    Wb[bufp][ws * 32 + fs * 16 + lg * 4 + i][wt * 32 + ft * 16 + l15] = f2bf(w);
                }
        __syncthreads();
        s16x8 wh[2][2];
#pragma unroll
        for (int fs = 0; fs < 2; ++fs) {
            const int sl = ws * 32 + fs * 16 + l15;
#pragma unroll
            for (int kc = 0; kc < 2; ++kc)
                wh[fs][kc] = *(const s16x8*)&Wb[bufp][sl][kc * 32 + lg * 8];
        }
#pragma unroll
        for (int fs = 0; fs < 2; ++fs)
#pragma unroll
            for (int fd = 0; fd < 2; ++fd)
#pragma unroll
                for (int kc = 0; kc < 2; ++kc)
                    o[fs][fd] = MFMA_BF16(wh[fs][kc], vP[fd][kc], o[fs][fd]);
    }

    // row sums: reduce 16 column-lanes, then the two wt waves
#pragma unroll
    for (int fs = 0; fs < 2; ++fs)
#pragma unroll
        for (int i = 0; i < 4; ++i) {
            float r = rowacc[fs][i];
            r += __shfl_xor(r, 1);
            r += __shfl_xor(r, 2);
            r += __shfl_xor(r, 4);
            r += __shfl_xor(r, 8);
            rowacc[fs][i] = r;
        }
    if (l15 == 0) {
#pragma unroll
        for (int fs = 0; fs < 2; ++fs)
#pragma unroll
            for (int i = 0; i < 4; ++i)
                rsum[wt][ws * 32 + fs * 16 + lg * 4 + i] = rowacc[fs][i];
    }
    __syncthreads();

#pragma unroll
    for (int fs = 0; fs < 2; ++fs)
#pragma unroll
        for (int i = 0; i < 4; ++i) {
            const int sl   = ws * 32 + fs * 16 + lg * 4 + i;
            const float inv = 1.0f / (rsum[0][sl] + rsum[1][sl]);
            const int srow = s0 + sl;
#pragma unroll
            for (int fd = 0; fd < 2; ++fd) {
                const int d = wt * 32 + fd * 16 + l15;
                float v = o[fs][fd][i] * inv;
                u16 hb = f2bf(v);
                u16 lb = f2bf(v - bf2f(hb));
                size_t idx = ((size_t)(b * S_LEN + srow)) * D_MODEL + h * DK + d;
                ATTNhi[idx] = hb;
                ATTNlo[idx] = lb;
            }
        }
}

extern "C" void kernel_launch(void* const* d_in, const int* in_sizes, int n_in,
                              void* d_out, int out_size, void* d_ws, size_t ws_size,
                              hipStream_t stream) {
    const float* queries = (const float*)d_in[0];
    const float* keys    = (const float*)d_in[1];
    const float* values  = (const float*)d_in[2];
    const float* Wq      = (const float*)d_in[3];
    const float* Wk      = (const float*)d_in[4];
    const float* Wv      = (const float*)d_in[5];
    const float* Wo      = (const float*)d_in[6];
    const float* bo      = (const float*)d_in[7];
    float* out = (float*)d_out;

    const size_t NW = (size_t)D_MODEL * D_MODEL;     // 1,048,576
    const size_t NX = (size_t)M_ROWS * D_MODEL;      // 8,388,608
    u16* base = (u16*)d_ws;
    size_t off = 0;
    auto take = [&](size_t n) { u16* r = base + off; off += n; return r; };
    u16 *Wqh = take(NW), *Wql = take(NW), *Wkh = take(NW), *Wkl = take(NW);
    u16 *Wvh = take(NW), *Wvl = take(NW), *Woh = take(NW), *Wol = take(NW);
    u16 *Xqh = take(NX), *Xql = take(NX);
    u16 *Xkh = take(NX), *Xkl = take(NX);
    u16 *Xvh = take(NX), *Xvl = take(NX);
    u16 *Qhi = take(NX), *Qlo = take(NX), *Khi = take(NX), *Klo = take(NX);
    u16 *VThi = take(NX);
    // reuse regions dead by the time these are written:
    u16* ATTNhi = Xqh;                 // dead after Q projection
    u16* ATTNlo = Xql;
    float* q2  = (float*)Xkh;          // dead after K projection
    float* k2  = q2 + (size_t)BH * S_LEN;
    float* CVa = k2 + (size_t)BH * S_LEN;

    // 1) split inputs/weights into hi/lo bf16
    split_bf16<<<(int)(NX / 8 / 256), 256, 0, stream>>>(queries, Xqh, Xql, (int)(NX / 8));
    split_bf16<<<(int)(NX / 8 / 256), 256, 0, stream>>>(keys,    Xkh, Xkl, (int)(NX / 8));
    split_bf16<<<(int)(NX / 8 / 256), 256, 0, stream>>>(values,  Xvh, Xvl, (int)(NX / 8));
    split_bf16<<<(int)(NW / 8 / 256), 256, 0, stream>>>(Wq, Wqh, Wql, (int)(NW / 8));
    split_bf16<<<(int)(NW / 8 / 256), 256, 0, stream>>>(Wk, Wkh, Wkl, (int)(NW / 8));
    split_bf16<<<(int)(NW / 8 / 256), 256, 0, stream>>>(Wv, Wvh, Wvl, (int)(NW / 8));
    split_bf16<<<(int)(NW / 8 / 256), 256, 0, stream>>>(Wo, Woh, Wol, (int)(NW / 8));

    // 2) projections (MFMA split-bf16)
    dim3 gproj(D_MODEL / 128, M_ROWS / 128);   // (8, 64)
    proj_mfma<0><<<gproj, 256, 0, stream>>>(Xqh, Xql, Wqh, Wql, nullptr, nullptr, Qhi, Qlo);
    proj_mfma<0><<<gproj, 256, 0, stream>>>(Xkh, Xkl, Wkh, Wkl, nullptr, nullptr, Khi, Klo);
    proj_mfma<2><<<gproj, 256, 0, stream>>>(Xvh, Xvl, Wvh, Wvl, nullptr, nullptr, VThi, nullptr);

    // 3) row norms
    row_norms<<<(2 * BH * S_LEN) / 4, 256, 0, stream>>>(Qhi, Qlo, Khi, Klo, q2, k2);

    // 4) column sums -> CV, then flash-style attention
    dim3 gpass(S_LEN / 64, BH);                // (32, 64)
    colsum_mfma<<<gpass, 256, 0, stream>>>(Qhi, Khi, q2, k2, CVa);
    attn_mfma<<<gpass, 256, 0, stream>>>(Qhi, Qlo, Khi, Klo, VThi, q2, k2, CVa, ATTNhi, ATTNlo);

    // 5) output projection + bias
    proj_mfma<1><<<gproj, 256, 0, stream>>>(ATTNhi, ATTNlo, Woh, Wol, bo, out, nullptr, nullptr);
}

// Round 8
// 1115.273 us; speedup vs baseline: 1.5900x; 1.5900x over previous
//
#include <hip/hip_runtime.h>

#define D_MODEL 1024
#define NHEADS  16
#define DK      64
#define S_LEN   2048
#define BATCH   4
#define BH      (BATCH * NHEADS)     // 64
#define M_ROWS  (BATCH * S_LEN)      // 8192

typedef float  f32x4 __attribute__((ext_vector_type(4)));
typedef short  s16x8 __attribute__((ext_vector_type(8)));
typedef unsigned short u16;
typedef u16 us8 __attribute__((ext_vector_type(8)));

__device__ __forceinline__ u16 f2bf(float f) {
    unsigned u = __builtin_bit_cast(unsigned, f);
    u += 0x7FFFu + ((u >> 16) & 1u);
    return (u16)(u >> 16);
}
__device__ __forceinline__ float bf2f(u16 b) {
    unsigned u = ((unsigned)b) << 16;
    return __builtin_bit_cast(float, u);
}
// packed fp32x2 -> bf16x2 (RNE), src0 -> low 16, src1 -> high 16
__device__ __forceinline__ unsigned cvt_pk_bf16(float lo, float hi) {
    unsigned r;
    asm("v_cvt_pk_bf16_f32 %0, %1, %2" : "=v"(r) : "v"(lo), "v"(hi));
    return r;
}

// compat = (1 + sqrt(max(d2,0))/64)^(-65) = exp2(-65 * log2(p))
__device__ __forceinline__ float compat_fn(float d2) {
    float g = __builtin_amdgcn_sqrtf(fmaxf(d2, 0.0f)) * 0.015625f;
    float p = 1.0f + g;
    return __builtin_amdgcn_exp2f(-65.0f * __builtin_amdgcn_logf(p));
}

__device__ __forceinline__ void gll16(const void* g, void* l) {
    __builtin_amdgcn_global_load_lds(
        (const __attribute__((address_space(1))) void*)g,
        (__attribute__((address_space(3))) void*)l, 16, 0, 0);
}

#define MFMA_BF16(a, b, c) __builtin_amdgcn_mfma_f32_16x16x32_bf16(a, b, c, 0, 0, 0)

// fp32 -> (hi, lo) bf16 split, 8 elements per thread
__global__ __launch_bounds__(256) void split_bf16(const float* __restrict__ in,
                                                  u16* __restrict__ hi,
                                                  u16* __restrict__ lo, int n8) {
    int i = blockIdx.x * 256 + threadIdx.x;
    if (i >= n8) return;
    const float4* p = (const float4*)in;
    float4 a = p[i * 2], b = p[i * 2 + 1];
    float v[8] = {a.x, a.y, a.z, a.w, b.x, b.y, b.z, b.w};
    us8 h, l;
#pragma unroll
    for (int j = 0; j < 8; ++j) {
        u16 hb = f2bf(v[j]);
        h[j] = hb;
        l[j] = f2bf(v[j] - bf2f(hb));
    }
    ((us8*)hi)[i] = h;
    ((us8*)lo)[i] = l;
}

// Split-bf16 MFMA GEMM: out = A @ B^T (+bias).   (unchanged from round 4)
template <int MODE>
__global__ __launch_bounds__(256, 2) void proj_mfma(
    const u16* __restrict__ Ah, const u16* __restrict__ Al,
    const u16* __restrict__ Bh, const u16* __restrict__ Bl,
    const float* __restrict__ bias,
    float* __restrict__ outf, u16* __restrict__ ohi, u16* __restrict__ olo) {
    __shared__ __align__(16) u16 lds[4 * 128 * 64];   // 64 KB
    u16* LAh = lds;
    u16* LAl = lds + 8192;
    u16* LBh = lds + 16384;
    u16* LBl = lds + 24576;

    const int tid  = threadIdx.x;
    const int wave = tid >> 6, lane = tid & 63;
    const int wm = wave >> 1, wn = wave & 1;
    const int l15 = lane & 15, lg = lane >> 4;
    const int flat = blockIdx.y * 8 + blockIdx.x;
    const int swz  = (flat & 7) * 64 + (flat >> 3);
    const int n0 = (swz & 7) * 128;
    const int m0 = (swz >> 3) * 128;

    const int srow = wave * 32 + (lane >> 3);
    const int scol = (lane & 7) * 8;

    f32x4 acc[4][4];
#pragma unroll
    for (int i = 0; i < 4; ++i)
#pragma unroll
        for (int j = 0; j < 4; ++j) acc[i][j] = (f32x4){0.f, 0.f, 0.f, 0.f};

#pragma unroll 1
    for (int k0 = 0; k0 < D_MODEL; k0 += 64) {
        __syncthreads();
#pragma unroll
        for (int q = 0; q < 4; ++q) {
            const size_t ga = (size_t)(m0 + srow + q * 8) * D_MODEL + k0 + scol;
            const size_t gb = (size_t)(n0 + srow + q * 8) * D_MODEL + k0 + scol;
            gll16(Ah + ga, LAh + wave * 2048 + q * 512);
            gll16(Al + ga, LAl + wave * 2048 + q * 512);
            gll16(Bh + gb, LBh + wave * 2048 + q * 512);
            gll16(Bl + gb, LBl + wave * 2048 + q * 512);
        }
        __syncthreads();
#pragma unroll
        for (int kc = 0; kc < 2; ++kc) {
            s16x8 ah[4], al[4];
#pragma unroll
            for (int fm = 0; fm < 4; ++fm) {
                const int r = wm * 64 + fm * 16 + l15;
                ah[fm] = *(const s16x8*)&LAh[r * 64 + kc * 32 + lg * 8];
                al[fm] = *(const s16x8*)&LAl[r * 64 + kc * 32 + lg * 8];
            }
#pragma unroll
            for (int fn = 0; fn < 4; ++fn) {
                const int r = wn * 64 + fn * 16 + l15;
                s16x8 bh = *(const s16x8*)&LBh[r * 64 + kc * 32 + lg * 8];
                s16x8 bl = *(const s16x8*)&LBl[r * 64 + kc * 32 + lg * 8];
#pragma unroll
                for (int fm = 0; fm < 4; ++fm) {
                    acc[fm][fn] = MFMA_BF16(ah[fm], bh, acc[fm][fn]);
                    acc[fm][fn] = MFMA_BF16(ah[fm], bl, acc[fm][fn]);
                    acc[fm][fn] = MFMA_BF16(al[fm], bh, acc[fm][fn]);
                }
            }
        }
    }
    __syncthreads();   // LDS free for epilogue reuse

    if (MODE == 0) {
        const int h = (n0 >> 6) + wn;
#pragma unroll
        for (int fm = 0; fm < 4; ++fm)
#pragma unroll
            for (int i = 0; i < 4; ++i) {
                const int m = m0 + wm * 64 + fm * 16 + lg * 4 + i;
                const int b = m >> 11, s = m & 2047;
                const size_t rb = ((size_t)((b * NHEADS + h) * S_LEN + s)) * DK;
#pragma unroll
                for (int fn = 0; fn < 4; ++fn) {
                    float v = acc[fm][fn][i];
                    u16 hb = f2bf(v);
                    u16 lb = f2bf(v - bf2f(hb));
                    ohi[rb + fn * 16 + l15] = hb;
                    olo[rb + fn * 16 + l15] = lb;
                }
            }
    } else if (MODE == 1) {
#pragma unroll
        for (int fm = 0; fm < 4; ++fm)
#pragma unroll
            for (int i = 0; i < 4; ++i) {
                const int m = m0 + wm * 64 + fm * 16 + lg * 4 + i;
#pragma unroll
                for (int fn = 0; fn < 4; ++fn) {
                    const int n = n0 + wn * 64 + fn * 16 + l15;
                    outf[(size_t)m * D_MODEL + n] = acc[fm][fn][i] + bias[n];
                }
            }
    } else {   // MODE 2: per-wave 64x64 transpose, HI only -> VT[bh][d][t]
        const int h  = (n0 >> 6) + wn;
        const int b  = m0 >> 11;
        const int bh = b * NHEADS + h;
        const int t_base = (m0 & 2047) + wm * 64;
        u16* T = lds + wave * 4096;   // [64][64] = [d_local][t_local]
#pragma unroll
        for (int fm = 0; fm < 4; ++fm)
#pragma unroll
            for (int fn = 0; fn < 4; ++fn)
#pragma unroll
                for (int i = 0; i < 4; ++i)
                    T[(fn * 16 + l15) * 64 + fm * 16 + lg * 4 + i] = f2bf(acc[fm][fn][i]);
        __syncthreads();
#pragma unroll
        for (int j = 0; j < 8; ++j) {
            const int cid = j * 64 + lane;
            const int dr = cid >> 3;
            const int cc = (cid & 7) * 8;
            us8 v8 = *(const us8*)&T[dr * 64 + cc];
            *(us8*)&ohi[((size_t)(bh * DK + dr)) * S_LEN + t_base + cc] = v8;
        }
    }
}

// squared L2 norms of Q rows and K rows from hi+lo bf16; one wave per row
__global__ __launch_bounds__(256) void row_norms(const u16* __restrict__ Qhi,
                                                 const u16* __restrict__ Qlo,
                                                 const u16* __restrict__ Khi,
                                                 const u16* __restrict__ Klo,
                                                 float* __restrict__ q2,
                                                 float* __restrict__ k2) {
    int wid  = blockIdx.x * 4 + (threadIdx.x >> 6);
    int lane = threadIdx.x & 63;
    const u16 *hi, *lo; float* dstp; int row;
    if (wid < BH * S_LEN) { hi = Qhi; lo = Qlo; dstp = q2; row = wid; }
    else                  { hi = Khi; lo = Klo; dstp = k2; row = wid - BH * S_LEN; }
    float v = bf2f(hi[(size_t)row * DK + lane]) + bf2f(lo[(size_t)row * DK + lane]);
    float s = v * v;
#pragma unroll
    for (int off = 32; off > 0; off >>= 1) s += __shfl_xor(s, off);
    if (lane == 0) dstp[row] = s;
}

// Pass A: column sums -> CV[t] = NC[t]^-0.5. SWAPPED operands: acc index i
// walks t, so k2 is a loop-invariant float4 and colacc is vector-indexed.
// Q-tile prefetch + one-iter compat deferral (small reg state).
__global__ __launch_bounds__(256, 4) void colsum_mfma(
    const u16* __restrict__ Qhi, const u16* __restrict__ Khi,
    const float* __restrict__ q2, const float* __restrict__ k2,
    float* __restrict__ CV) {
    const int tid  = threadIdx.x;
    const int wave = tid >> 6, lane = tid & 63;
    const int ws = wave >> 1, wt = wave & 1;
    const int l15 = lane & 15, lg = lane >> 4;
    const int flat = blockIdx.y * 32 + blockIdx.x;
    const int swz  = (flat & 7) * 256 + (flat >> 3);
    const int bh = swz >> 5;
    const int t0 = (swz & 31) * 64;
    const size_t base = (size_t)bh * S_LEN * DK;
    const u16* Kh = Khi + base;
    const u16* Qh = Qhi + base;
    const float* q2b = q2 + (size_t)bh * S_LEN;
    const float* k2b = k2 + (size_t)bh * S_LEN;

    s16x8 kh[2][2];
    float4 k24[2];   // loop-invariant (t fixed per block)
#pragma unroll
    for (int ft = 0; ft < 2; ++ft) {
        const int tr = t0 + wt * 32 + ft * 16 + l15;
#pragma unroll
        for (int kc = 0; kc < 2; ++kc)
            kh[ft][kc] = *(const s16x8*)(Kh + (size_t)tr * DK + kc * 32 + lg * 8);
        k24[ft] = *(const float4*)&k2b[t0 + wt * 32 + ft * 16 + lg * 4];
    }

    s16x8 qh[2][2];
    auto loadQ = [&](int sb) {
#pragma unroll
        for (int fs = 0; fs < 2; ++fs) {
            const int qr = sb + fs * 16 + l15;
#pragma unroll
            for (int kc = 0; kc < 2; ++kc)
                qh[fs][kc] = *(const s16x8*)(Qh + (size_t)qr * DK + kc * 32 + lg * 8);
        }
    };
    loadQ(ws * 32);

    f32x4 colacc[2];
    colacc[0] = (f32x4){0.f, 0.f, 0.f, 0.f};
    colacc[1] = (f32x4){0.f, 0.f, 0.f, 0.f};
    f32x4 accP[2][2];
    float q2P[2];

#pragma unroll 1
    for (int s0 = 0; s0 < S_LEN; s0 += 64) {
        const int sb = s0 + ws * 32;
        float q2c[2];
#pragma unroll
        for (int fs = 0; fs < 2; ++fs) q2c[fs] = q2b[sb + fs * 16 + l15];

        f32x4 accC[2][2];
#pragma unroll
        for (int fs = 0; fs < 2; ++fs)
#pragma unroll
            for (int ft = 0; ft < 2; ++ft) {
                accC[fs][ft] = (f32x4){0.f, 0.f, 0.f, 0.f};
#pragma unroll
                for (int kc = 0; kc < 2; ++kc)
                    accC[fs][ft] = MFMA_BF16(kh[ft][kc], qh[fs][kc], accC[fs][ft]);
            }
        if (s0 + 64 < S_LEN) loadQ(s0 + 64 + ws * 32);   // prefetch next s-tile

        if (s0 > 0) {   // deferred compat on PREVIOUS acc (MFMAs above drain)
#pragma unroll
            for (int fs = 0; fs < 2; ++fs)
#pragma unroll
                for (int ft = 0; ft < 2; ++ft)
#pragma unroll
                    for (int i = 0; i < 4; ++i) {
                        float d2 = fmaf(-2.0f, accP[fs][ft][i], q2P[fs] + k24[ft][i]);
                        colacc[ft][i] += compat_fn(d2);
                    }
        }
#pragma unroll
        for (int fs = 0; fs < 2; ++fs) {
            q2P[fs] = q2c[fs];
#pragma unroll
            for (int ft = 0; ft < 2; ++ft) accP[fs][ft] = accC[fs][ft];
        }
    }
#pragma unroll
    for (int fs = 0; fs < 2; ++fs)
#pragma unroll
        for (int ft = 0; ft < 2; ++ft)
#pragma unroll
            for (int i = 0; i < 4; ++i) {
                float d2 = fmaf(-2.0f, accP[fs][ft][i], q2P[fs] + k24[ft][i]);
                colacc[ft][i] += compat_fn(d2);
            }

    // reduce across the 16 s-lanes (l15 = bits 0..3)
#pragma unroll
    for (int ft = 0; ft < 2; ++ft)
#pragma unroll
        for (int i = 0; i < 4; ++i) {
            float r = colacc[ft][i];
            r += __shfl_xor(r, 1);
            r += __shfl_xor(r, 2);
            r += __shfl_xor(r, 4);
            r += __shfl_xor(r, 8);
            colacc[ft][i] = r;
        }
    __shared__ float cs[4][64];
    if (l15 == 0) {
#pragma unroll
        for (int ft = 0; ft < 2; ++ft)
#pragma unroll
            for (int i = 0; i < 4; ++i)
                cs[wave][wt * 32 + ft * 16 + lg * 4 + i] = colacc[ft][i];
    }
    __syncthreads();
    if (tid < 64) {
        int wtj = tid >> 5;
        float s = cs[wtj][tid] + cs[wtj + 2][tid];
        CV[(size_t)bh * S_LEN + t0 + tid] = 1.0f / __builtin_amdgcn_sqrtf(s);
    }
}

// Pass B: flash-style, r4 dataflow + SWAPPED QK operands.
// acc index i walks t -> the 4 W values per (fs,ft) are row-contiguous:
// 2x v_cvt_pk_bf16_f32 + 1x ds_write_b64 replaces 4x f2bf + 4x ds_write_b16.
// V at iter top, K prefetched 1 iter ahead, W double-buffered, ONE barrier/iter.
__global__ __launch_bounds__(256, 4) void attn_mfma(
    const u16* __restrict__ Qhi, const u16* __restrict__ Qlo,
    const u16* __restrict__ Khi, const u16* __restrict__ Klo,
    const u16* __restrict__ VThi,
    const float* __restrict__ q2, const float* __restrict__ k2,
    const float* __restrict__ CV,
    u16* __restrict__ ATTNhi, u16* __restrict__ ATTNlo) {
    __shared__ __align__(16) u16 Wb[2][64][72];   // double-buffered [s][t]
    __shared__ float rsum[2][64];
    const int tid  = threadIdx.x;
    const int wave = tid >> 6, lane = tid & 63;
    const int ws = wave >> 1, wt = wave & 1;
    const int l15 = lane & 15, lg = lane >> 4;
    const int flat = blockIdx.y * 32 + blockIdx.x;
    const int swz  = (flat & 7) * 256 + (flat >> 3);
    const int bh = swz >> 5;
    const int s0 = (swz & 31) * 64;
    const int b = bh >> 4, h = bh & 15;
    const size_t base = (size_t)bh * S_LEN * DK;
    const u16* Qh = Qhi + base;
    const u16* Ql = Qlo + base;
    const u16* Kh = Khi + base;
    const u16* Kl = Klo + base;
    const u16* Vh = VThi + base;   // per-bh [64][2048]
    const float* q2b = q2 + (size_t)bh * S_LEN;
    const float* k2b = k2 + (size_t)bh * S_LEN;
    const float* CVb = CV + (size_t)bh * S_LEN;

    s16x8 qh[2][2], qlr[2][2];
    float q2s[2];
#pragma unroll
    for (int fs = 0; fs < 2; ++fs) {
        const int qr = s0 + ws * 32 + fs * 16 + l15;
#pragma unroll
        for (int kc = 0; kc < 2; ++kc) {
            qh[fs][kc]  = *(const s16x8*)(Qh + (size_t)qr * DK + kc * 32 + lg * 8);
            qlr[fs][kc] = *(const s16x8*)(Ql + (size_t)qr * DK + kc * 32 + lg * 8);
        }
        q2s[fs] = q2b[qr];
    }

    s16x8 kh[2][2], kl[2][2];
    auto loadK = [&](int tc) {
#pragma unroll
        for (int ft = 0; ft < 2; ++ft) {
            const int tr = tc + wt * 32 + ft * 16 + l15;
#pragma unroll
            for (int kc = 0; kc < 2; ++kc) {
                kh[ft][kc] = *(const s16x8*)(Kh + (size_t)tr * DK + kc * 32 + lg * 8);
                kl[ft][kc] = *(const s16x8*)(Kl + (size_t)tr * DK + kc * 32 + lg * 8);
            }
        }
    };
    loadK(0);

    f32x4 o[2][2];
#pragma unroll
    for (int fs = 0; fs < 2; ++fs)
#pragma unroll
        for (int fd = 0; fd < 2; ++fd)
            o[fs][fd] = (f32x4){0.f, 0.f, 0.f, 0.f};
    float rowacc[2] = {0.f, 0.f};

#pragma unroll 1
    for (int it = 0; it < S_LEN / 64; ++it) {
        const int t0 = it * 64;
        const int buf = it & 1;
        // V (single-bf16) for CURRENT iter: consumed after QK/barrier
        s16x8 vv[2][2];
#pragma unroll
        for (int fd = 0; fd < 2; ++fd) {
            const int dr = wt * 32 + fd * 16 + l15;
#pragma unroll
            for (int kc = 0; kc < 2; ++kc)
                vv[fd][kc] = *(const s16x8*)(Vh + (size_t)dr * S_LEN + t0 + kc * 32 + lg * 8);
        }
        float4 k24[2], cv4[2];
#pragma unroll
        for (int ft = 0; ft < 2; ++ft) {
            const int tr4 = t0 + wt * 32 + ft * 16 + lg * 4;
            k24[ft] = *(const float4*)&k2b[tr4];
            cv4[ft] = *(const float4*)&CVb[tr4];
        }

        // QK^T SWAPPED (A=K, B=Q): acc row i -> t, col lane -> s
        f32x4 acc[2][2];
#pragma unroll
        for (int fs = 0; fs < 2; ++fs)
#pragma unroll
            for (int ft = 0; ft < 2; ++ft) {
                acc[fs][ft] = (f32x4){0.f, 0.f, 0.f, 0.f};
#pragma unroll
                for (int kc = 0; kc < 2; ++kc) {
                    acc[fs][ft] = MFMA_BF16(kh[ft][kc], qh[fs][kc],  acc[fs][ft]);
                    acc[fs][ft] = MFMA_BF16(kl[ft][kc], qh[fs][kc],  acc[fs][ft]);
                    acc[fs][ft] = MFMA_BF16(kh[ft][kc], qlr[fs][kc], acc[fs][ft]);
                }
            }
        // prefetch NEXT K tile (lands during compat+barrier+PV)
        if (t0 + 64 < S_LEN) loadK(t0 + 64);

        // compat -> w -> packed bf16 pair -> ds_write_b64 (row-contiguous in t)
#pragma unroll
        for (int fs = 0; fs < 2; ++fs) {
            const int sl = ws * 32 + fs * 16 + l15;
#pragma unroll
            for (int ft = 0; ft < 2; ++ft) {
                float w[4];
#pragma unroll
                for (int i = 0; i < 4; ++i) {
                    float d2 = fmaf(-2.0f, acc[fs][ft][i], q2s[fs] + k24[ft][i]);
                    w[i] = compat_fn(d2) * cv4[ft][i];
                    rowacc[fs] += w[i];
                }
                unsigned p0 = cvt_pk_bf16(w[0], w[1]);
                unsigned p1 = cvt_pk_bf16(w[2], w[3]);
                *(unsigned long long*)&Wb[buf][sl][wt * 32 + ft * 16 + lg * 4] =
                    (unsigned long long)p0 | ((unsigned long long)p1 << 32);
            }
        }
        __syncthreads();   // W[buf] complete (prev iter used buf^1)

        // PV: A=W rows s, k=t; B=V^T
        s16x8 wh[2][2];
#pragma unroll
        for (int fs = 0; fs < 2; ++fs) {
            const int sl = ws * 32 + fs * 16 + l15;
#pragma unroll
            for (int kc = 0; kc < 2; ++kc)
                wh[fs][kc] = *(const s16x8*)&Wb[buf][sl][kc * 32 + lg * 8];
        }
#pragma unroll
        for (int fs = 0; fs < 2; ++fs)
#pragma unroll
            for (int fd = 0; fd < 2; ++fd)
#pragma unroll
                for (int kc = 0; kc < 2; ++kc)
                    o[fs][fd] = MFMA_BF16(wh[fs][kc], vv[fd][kc], o[fs][fd]);
    }

    // row sums: lane holds partial for row s=(..+l15) over its t-subset;
    // reduce across lg (bits 4,5), then across the two wt waves via LDS
#pragma unroll
    for (int fs = 0; fs < 2; ++fs) {
        float r = rowacc[fs];
        r += __shfl_xor(r, 16);
        r += __shfl_xor(r, 32);
        rowacc[fs] = r;
    }
    if (lg == 0) {
#pragma unroll
        for (int fs = 0; fs < 2; ++fs)
            rsum[wt][ws * 32 + fs * 16 + l15] = rowacc[fs];
    }
    __syncthreads();

#pragma unroll
    for (int fs = 0; fs < 2; ++fs)
#pragma unroll
        for (int i = 0; i < 4; ++i) {
            const int sl   = ws * 32 + fs * 16 + lg * 4 + i;
            const float inv = 1.0f / (rsum[0][sl] + rsum[1][sl]);
            const int srow = s0 + sl;
#pragma unroll
            for (int fd = 0; fd < 2; ++fd) {
                const int d = wt * 32 + fd * 16 + l15;
                float v = o[fs][fd][i] * inv;
                u16 hb = f2bf(v);
                u16 lb = f2bf(v - bf2f(hb));
                size_t idx = ((size_t)(b * S_LEN + srow)) * D_MODEL + h * DK + d;
                ATTNhi[idx] = hb;
                ATTNlo[idx] = lb;
            }
        }
}

extern "C" void kernel_launch(void* const* d_in, const int* in_sizes, int n_in,
                              void* d_out, int out_size, void* d_ws, size_t ws_size,
                              hipStream_t stream) {
    const float* queries = (const float*)d_in[0];
    const float* keys    = (const float*)d_in[1];
    const float* values  = (const float*)d_in[2];
    const float* Wq      = (const float*)d_in[3];
    const float* Wk      = (const float*)d_in[4];
    const float* Wv      = (const float*)d_in[5];
    const float* Wo      = (const float*)d_in[6];
    const float* bo      = (const float*)d_in[7];
    float* out = (float*)d_out;

    const size_t NW = (size_t)D_MODEL * D_MODEL;     // 1,048,576
    const size_t NX = (size_t)M_ROWS * D_MODEL;      // 8,388,608
    u16* base = (u16*)d_ws;
    size_t off = 0;
    auto take = [&](size_t n) { u16* r = base + off; off += n; return r; };
    u16 *Wqh = take(NW), *Wql = take(NW), *Wkh = take(NW), *Wkl = take(NW);
    u16 *Wvh = take(NW), *Wvl = take(NW), *Woh = take(NW), *Wol = take(NW);
    u16 *Xqh = take(NX), *Xql = take(NX);
    u16 *Xkh = take(NX), *Xkl = take(NX);
    u16 *Xvh = take(NX), *Xvl = take(NX);
    u16 *Qhi = take(NX), *Qlo = take(NX), *Khi = take(NX), *Klo = take(NX);
    u16 *VThi = take(NX);
    // reuse regions dead by the time these are written:
    u16* ATTNhi = Xqh;                 // dead after Q projection
    u16* ATTNlo = Xql;
    float* q2  = (float*)Xkh;          // dead after K projection
    float* k2  = q2 + (size_t)BH * S_LEN;
    float* CVa = k2 + (size_t)BH * S_LEN;

    // 1) split inputs/weights into hi/lo bf16
    split_bf16<<<(int)(NX / 8 / 256), 256, 0, stream>>>(queries, Xqh, Xql, (int)(NX / 8));
    split_bf16<<<(int)(NX / 8 / 256), 256, 0, stream>>>(keys,    Xkh, Xkl, (int)(NX / 8));
    split_bf16<<<(int)(NX / 8 / 256), 256, 0, stream>>>(values,  Xvh, Xvl, (int)(NX / 8));
    split_bf16<<<(int)(NW / 8 / 256), 256, 0, stream>>>(Wq, Wqh, Wql, (int)(NW / 8));
    split_bf16<<<(int)(NW / 8 / 256), 256, 0, stream>>>(Wk, Wkh, Wkl, (int)(NW / 8));
    split_bf16<<<(int)(NW / 8 / 256), 256, 0, stream>>>(Wv, Wvh, Wvl, (int)(NW / 8));
    split_bf16<<<(int)(NW / 8 / 256), 256, 0, stream>>>(Wo, Woh, Wol, (int)(NW / 8));

    // 2) projections (MFMA split-bf16)
    dim3 gproj(D_MODEL / 128, M_ROWS / 128);   // (8, 64)
    proj_mfma<0><<<gproj, 256, 0, stream>>>(Xqh, Xql, Wqh, Wql, nullptr, nullptr, Qhi, Qlo);
    proj_mfma<0><<<gproj, 256, 0, stream>>>(Xkh, Xkl, Wkh, Wkl, nullptr, nullptr, Khi, Klo);
    proj_mfma<2><<<gproj, 256, 0, stream>>>(Xvh, Xvl, Wvh, Wvl, nullptr, nullptr, VThi, nullptr);

    // 3) row norms
    row_norms<<<(2 * BH * S_LEN) / 4, 256, 0, stream>>>(Qhi, Qlo, Khi, Klo, q2, k2);

    // 4) column sums -> CV, then flash-style attention
    dim3 gpass(S_LEN / 64, BH);                // (32, 64)
    colsum_mfma<<<gpass, 256, 0, stream>>>(Qhi, Khi, q2, k2, CVa);
    attn_mfma<<<gpass, 256, 0, stream>>>(Qhi, Qlo, Khi, Klo, VThi, q2, k2, CVa, ATTNhi, ATTNlo);

    // 5) output projection + bias
    proj_mfma<1><<<gproj, 256, 0, stream>>>(ATTNhi, ATTNlo, Woh, Wol, bo, out, nullptr, nullptr);
}